// Round 3
// baseline (739.946 us; speedup 1.0000x reference)
//
#include <hip/hip_runtime.h>

// GCN 2-layer: x[N,1] -> GCNConv(1,16) relu -> GCNConv(16,2) -> log_softmax
// Structure exploited:
//   layer1: h = x @ W1 is rank-1 => scatter reduces to scalar s[n] = sum norm*x[src]
//   layer2: gather operand g[n] = (relu(s*W1+b1)) @ W2 is 2 floats/node
// Passes: zero -> deg scatter -> dinv -> s scatter -> g -> agg2 scatter (into d_out)
//         -> logsoftmax (in-place on d_out)
// NOTE: harness delivers integer inputs as int32 (edge_index is const int*, NOT
// long long — casting to int64 caused the round-1/2 OOB-atomic abort).

static constexpr int BLOCK = 256;

__global__ void zero_kernel(float* __restrict__ a,   // ws: deg + s (2N floats)
                            float* __restrict__ b,   // d_out (2N floats)
                            int n2) {
    int i = blockIdx.x * blockDim.x + threadIdx.x;
    if (i < n2) {
        a[i] = 0.0f;
        b[i] = 0.0f;
    }
}

__global__ void deg_kernel(const int* __restrict__ dst,
                           const float* __restrict__ w,
                           float* __restrict__ deg, int E) {
    int e = blockIdx.x * blockDim.x + threadIdx.x;
    if (e < E) {
        atomicAdd(&deg[dst[e]], w[e]);
    }
}

__global__ void dinv_kernel(float* __restrict__ deg, int N) {
    int n = blockIdx.x * blockDim.x + threadIdx.x;
    if (n < N) {
        float d = deg[n] + 1.0f;                  // self-loop fill value 1.0
        deg[n] = (d > 0.0f) ? rsqrtf(d) : 0.0f;   // in-place -> dinv
    }
}

__global__ void s_kernel(const int* __restrict__ src,
                         const int* __restrict__ dst,
                         const float* __restrict__ w,
                         const float* __restrict__ dinv,
                         const float* __restrict__ x,
                         float* __restrict__ s, int E) {
    int e = blockIdx.x * blockDim.x + threadIdx.x;
    if (e < E) {
        int si = src[e];
        int di = dst[e];
        float norm = dinv[si] * w[e] * dinv[di];
        atomicAdd(&s[di], norm * x[si]);
    }
}

__global__ void g_kernel(const float* __restrict__ s,
                         const float* __restrict__ dinv,
                         const float* __restrict__ x,
                         const float* __restrict__ W1,   // [1,16]
                         const float* __restrict__ b1,   // [16]
                         const float* __restrict__ W2,   // [16,2] row-major
                         float2* __restrict__ g, int N) {
    int n = blockIdx.x * blockDim.x + threadIdx.x;
    if (n < N) {
        float dv = dinv[n];
        // self-loop contribution to layer-1 aggregation: norm_loop = dv*dv
        float sv = s[n] + dv * dv * x[n];
        float g0 = 0.0f, g1 = 0.0f;
#pragma unroll
        for (int f = 0; f < 16; ++f) {
            float h = fmaxf(sv * W1[f] + b1[f], 0.0f);   // relu(layer1)
            g0 += h * W2[2 * f + 0];
            g1 += h * W2[2 * f + 1];
        }
        g[n] = make_float2(g0, g1);
    }
}

__global__ void agg2_kernel(const int* __restrict__ src,
                            const int* __restrict__ dst,
                            const float* __restrict__ w,
                            const float* __restrict__ dinv,
                            const float2* __restrict__ g,
                            float* __restrict__ agg,     // = d_out, [2N]
                            int E) {
    int e = blockIdx.x * blockDim.x + threadIdx.x;
    if (e < E) {
        int si = src[e];
        int di = dst[e];
        float norm = dinv[si] * w[e] * dinv[di];
        float2 gv = g[si];
        atomicAdd(&agg[2 * di + 0], norm * gv.x);
        atomicAdd(&agg[2 * di + 1], norm * gv.y);
    }
}

__global__ void out_kernel(float* __restrict__ out,      // in: agg, out: log_softmax
                           const float* __restrict__ dinv,
                           const float2* __restrict__ g,
                           const float* __restrict__ b2,  // [2]
                           int N) {
    int n = blockIdx.x * blockDim.x + threadIdx.x;
    if (n < N) {
        float dv2 = dinv[n] * dinv[n];
        float2 gv = g[n];
        float a0 = out[2 * n + 0] + dv2 * gv.x + b2[0];
        float a1 = out[2 * n + 1] + dv2 * gv.y + b2[1];
        float m = fmaxf(a0, a1);
        float lse = m + logf(expf(a0 - m) + expf(a1 - m));
        out[2 * n + 0] = a0 - lse;
        out[2 * n + 1] = a1 - lse;
    }
}

extern "C" void kernel_launch(void* const* d_in, const int* in_sizes, int n_in,
                              void* d_out, int out_size, void* d_ws, size_t ws_size,
                              hipStream_t stream) {
    const float* x  = (const float*)d_in[0];
    const int*   ei = (const int*)d_in[1];     // [2, E] delivered as int32
    const float* w  = (const float*)d_in[2];
    const float* W1 = (const float*)d_in[3];
    const float* b1 = (const float*)d_in[4];
    const float* W2 = (const float*)d_in[5];
    const float* b2 = (const float*)d_in[6];
    float* out = (float*)d_out;

    const int N = in_sizes[0];          // 100000 (x is [N,1])
    const int E = in_sizes[2];          // 3200000 (edge_weight count)

    const int* src = ei;
    const int* dst = ei + E;

    // workspace layout (floats): [0,N) deg/dinv | [N,2N) s | [2N,4N) g(float2)
    float*  ws   = (float*)d_ws;
    float*  dinv = ws;
    float*  s    = ws + (size_t)N;
    float2* g    = (float2*)(ws + (size_t)2 * N);

    const int gridE  = (E + BLOCK - 1) / BLOCK;
    const int gridN  = (N + BLOCK - 1) / BLOCK;
    const int gridN2 = (2 * N + BLOCK - 1) / BLOCK;

    zero_kernel<<<gridN2, BLOCK, 0, stream>>>(ws, out, 2 * N);  // deg+s and d_out
    deg_kernel <<<gridE,  BLOCK, 0, stream>>>(dst, w, dinv, E);
    dinv_kernel<<<gridN,  BLOCK, 0, stream>>>(dinv, N);
    s_kernel   <<<gridE,  BLOCK, 0, stream>>>(src, dst, w, dinv, x, s, E);
    g_kernel   <<<gridN,  BLOCK, 0, stream>>>(s, dinv, x, W1, b1, W2, g, N);
    agg2_kernel<<<gridE,  BLOCK, 0, stream>>>(src, dst, w, dinv, g, out, E);
    out_kernel <<<gridN,  BLOCK, 0, stream>>>(out, dinv, g, b2, N);
}

// Round 4
// 255.493 us; speedup vs baseline: 2.8962x; 2.8962x over previous
//
#include <hip/hip_runtime.h>
#include <math.h>

// GCN 2-layer, N=100K nodes, E=3.2M edges, feat 1 -> 16 -> 2, log_softmax.
//
// R3 lesson (rocprof): device-scope fp32 atomicAdd on gfx950 is write-through
// at 32 B/op (per-XCD L2 non-coherent -> atomics execute at memory side).
// 12.8M atomics = ~410 MB fabric writes = ~570 us of the 740 us total.
//
// R4 design: counting-sort edges by dst into buckets of 128 nodes (payload
// u64 = w<<32 | src<<7 | dstLow). All aggregations then run in LDS with
// coalesced reads of the sorted payload (L3-resident, 25.6 MB) and coalesced
// writes. Zero global float atomics. 2-class log_softmax depends only on
// d = a1-a0, so layer 2 scatters a single scalar gamma = g1-g0 per node.
// Falls back to the R3 atomic path if ws_size is too small.

static constexpr int BLOCK = 256;
static constexpr int CHUNK = 128;    // nodes per bucket (pow2)
static constexpr int EPB   = 8192;   // edges per block in sort phase
static constexpr int MAXNB = 1024;   // LDS histogram capacity

// ======================= sorted-bucket path =======================

__global__ void zero_counts_kernel(unsigned int* __restrict__ cnt, int nb) {
    int i = blockIdx.x * blockDim.x + threadIdx.x;
    if (i < nb) cnt[i] = 0u;
}

__global__ void hist_kernel(const int* __restrict__ dst,
                            unsigned int* __restrict__ cnt,
                            int E, int nb) {
    __shared__ unsigned int h[MAXNB];
    for (int i = threadIdx.x; i < nb; i += BLOCK) h[i] = 0u;
    __syncthreads();
    int base = blockIdx.x * EPB;
    for (int k = 0; k < EPB / BLOCK; ++k) {
        int e = base + k * BLOCK + threadIdx.x;
        if (e < E) atomicAdd(&h[dst[e] / CHUNK], 1u);
    }
    __syncthreads();
    for (int i = threadIdx.x; i < nb; i += BLOCK) {
        unsigned int c = h[i];
        if (c) atomicAdd(&cnt[i], c);
    }
}

__global__ void scan_kernel(const unsigned int* __restrict__ cnt,
                            unsigned int* __restrict__ start,   // nb+1
                            unsigned int* __restrict__ cursor,  // nb
                            int nb) {
    __shared__ unsigned int s[MAXNB];
    int t = threadIdx.x;
    unsigned int c = (t < nb) ? cnt[t] : 0u;
    s[t] = c;
    __syncthreads();
    for (int off = 1; off < MAXNB; off <<= 1) {
        unsigned int v = (t >= off) ? s[t - off] : 0u;
        __syncthreads();
        s[t] += v;
        __syncthreads();
    }
    if (t < nb) { start[t + 1] = s[t]; cursor[t] = s[t] - c; }
    if (t == 0) start[0] = 0u;
}

__global__ void scatter_kernel(const int* __restrict__ src,
                               const int* __restrict__ dst,
                               const float* __restrict__ w,
                               unsigned int* __restrict__ cursor,
                               unsigned long long* __restrict__ payload,
                               int E, int nb) {
    __shared__ unsigned int h[MAXNB];
    for (int i = threadIdx.x; i < nb; i += BLOCK) h[i] = 0u;
    __syncthreads();
    int base = blockIdx.x * EPB;
    // pass 1: block-local bucket counts
    for (int k = 0; k < EPB / BLOCK; ++k) {
        int e = base + k * BLOCK + threadIdx.x;
        if (e < E) atomicAdd(&h[dst[e] / CHUNK], 1u);
    }
    __syncthreads();
    // reserve contiguous global space per bucket; h[b] becomes running slot
    for (int i = threadIdx.x; i < nb; i += BLOCK) {
        unsigned int c = h[i];
        if (c) h[i] = atomicAdd(&cursor[i], c);
    }
    __syncthreads();
    // pass 2: emit packed payloads
    for (int k = 0; k < EPB / BLOCK; ++k) {
        int e = base + k * BLOCK + threadIdx.x;
        if (e < E) {
            int d = dst[e];
            int b = d / CHUNK;
            unsigned int slot = atomicAdd(&h[b], 1u);
            unsigned long long p =
                ((unsigned long long)__float_as_uint(w[e]) << 32) |
                ((unsigned int)src[e] << 7) |
                (unsigned int)(d & (CHUNK - 1));
            payload[slot] = p;
        }
    }
}

__global__ void deg_dinv_kernel(const unsigned long long* __restrict__ payload,
                                const unsigned int* __restrict__ start,
                                float* __restrict__ dinv, int N) {
    __shared__ float acc[CHUNK];
    int b = blockIdx.x, t = threadIdx.x;
    if (t < CHUNK) acc[t] = 0.0f;
    __syncthreads();
    unsigned int s0 = start[b], s1 = start[b + 1];
    for (unsigned int i = s0 + t; i < s1; i += BLOCK) {
        unsigned long long p = payload[i];
        float wv = __uint_as_float((unsigned int)(p >> 32));
        atomicAdd(&acc[(unsigned int)p & (CHUNK - 1)], wv);
    }
    __syncthreads();
    int n = b * CHUNK + t;
    if (t < CHUNK && n < N) {
        float d = acc[t] + 1.0f;                  // self-loop fill 1.0
        dinv[n] = (d > 0.0f) ? rsqrtf(d) : 0.0f;
    }
}

__global__ void s_gamma_kernel(const unsigned long long* __restrict__ payload,
                               const unsigned int* __restrict__ start,
                               const float* __restrict__ dinv,
                               const float* __restrict__ x,
                               const float* __restrict__ W1,   // [16]
                               const float* __restrict__ b1,   // [16]
                               const float* __restrict__ W2,   // [16][2]
                               float* __restrict__ gamma, int N) {
    __shared__ float acc[CHUNK];
    __shared__ float dloc[CHUNK];
    int b = blockIdx.x, t = threadIdx.x;
    if (t < CHUNK) {
        acc[t] = 0.0f;
        int n = b * CHUNK + t;
        dloc[t] = (n < N) ? dinv[n] : 0.0f;
    }
    __syncthreads();
    unsigned int s0 = start[b], s1 = start[b + 1];
    for (unsigned int i = s0 + t; i < s1; i += BLOCK) {
        unsigned long long p = payload[i];
        float wv = __uint_as_float((unsigned int)(p >> 32));
        unsigned int lo = (unsigned int)p;
        int si = (int)(lo >> 7);
        int dl = (int)(lo & (CHUNK - 1));
        float norm = dinv[si] * wv * dloc[dl];
        atomicAdd(&acc[dl], norm * x[si]);
    }
    __syncthreads();
    int n = b * CHUNK + t;
    if (t < CHUNK && n < N) {
        float dv = dloc[t];
        float sv = acc[t] + dv * dv * x[n];       // + self-loop msg
        float gd = 0.0f;
#pragma unroll
        for (int f = 0; f < 16; ++f) {
            float h = fmaxf(sv * W1[f] + b1[f], 0.0f);   // relu(layer1)
            gd += h * (W2[2 * f + 1] - W2[2 * f + 0]);   // g1 - g0
        }
        gamma[n] = gd;
    }
}

__global__ void d_out_kernel(const unsigned long long* __restrict__ payload,
                             const unsigned int* __restrict__ start,
                             const float* __restrict__ dinv,
                             const float* __restrict__ gamma,
                             const float* __restrict__ b2,    // [2]
                             float* __restrict__ out, int N) {
    __shared__ float acc[CHUNK];
    __shared__ float dloc[CHUNK];
    int b = blockIdx.x, t = threadIdx.x;
    if (t < CHUNK) {
        acc[t] = 0.0f;
        int n = b * CHUNK + t;
        dloc[t] = (n < N) ? dinv[n] : 0.0f;
    }
    __syncthreads();
    unsigned int s0 = start[b], s1 = start[b + 1];
    for (unsigned int i = s0 + t; i < s1; i += BLOCK) {
        unsigned long long p = payload[i];
        float wv = __uint_as_float((unsigned int)(p >> 32));
        unsigned int lo = (unsigned int)p;
        int si = (int)(lo >> 7);
        int dl = (int)(lo & (CHUNK - 1));
        float norm = dinv[si] * wv * dloc[dl];
        atomicAdd(&acc[dl], norm * gamma[si]);
    }
    __syncthreads();
    int n = b * CHUNK + t;
    if (t < CHUNK && n < N) {
        float dv = dloc[t];
        float d = acc[t] + dv * dv * gamma[n] + (b2[1] - b2[0]);
        // log_softmax over {a0, a1} depends only on d = a1 - a0:
        // lse = log(1 + e^d) computed stably
        float lse = fmaxf(d, 0.0f) + log1pf(expf(-fabsf(d)));
        out[2 * n + 0] = -lse;
        out[2 * n + 1] = d - lse;
    }
}

// ======================= legacy atomic path (R3, fallback) =======================

__global__ void zero_kernel(float* __restrict__ a, float* __restrict__ b, int n2) {
    int i = blockIdx.x * blockDim.x + threadIdx.x;
    if (i < n2) { a[i] = 0.0f; b[i] = 0.0f; }
}
__global__ void deg_kernel(const int* __restrict__ dst, const float* __restrict__ w,
                           float* __restrict__ deg, int E) {
    int e = blockIdx.x * blockDim.x + threadIdx.x;
    if (e < E) atomicAdd(&deg[dst[e]], w[e]);
}
__global__ void dinv_kernel(float* __restrict__ deg, int N) {
    int n = blockIdx.x * blockDim.x + threadIdx.x;
    if (n < N) {
        float d = deg[n] + 1.0f;
        deg[n] = (d > 0.0f) ? rsqrtf(d) : 0.0f;
    }
}
__global__ void s_kernel(const int* __restrict__ src, const int* __restrict__ dst,
                         const float* __restrict__ w, const float* __restrict__ dinv,
                         const float* __restrict__ x, float* __restrict__ s, int E) {
    int e = blockIdx.x * blockDim.x + threadIdx.x;
    if (e < E) {
        int si = src[e], di = dst[e];
        atomicAdd(&s[di], dinv[si] * w[e] * dinv[di] * x[si]);
    }
}
__global__ void g_kernel(const float* __restrict__ s, const float* __restrict__ dinv,
                         const float* __restrict__ x, const float* __restrict__ W1,
                         const float* __restrict__ b1, const float* __restrict__ W2,
                         float2* __restrict__ g, int N) {
    int n = blockIdx.x * blockDim.x + threadIdx.x;
    if (n < N) {
        float dv = dinv[n];
        float sv = s[n] + dv * dv * x[n];
        float g0 = 0.0f, g1 = 0.0f;
#pragma unroll
        for (int f = 0; f < 16; ++f) {
            float h = fmaxf(sv * W1[f] + b1[f], 0.0f);
            g0 += h * W2[2 * f + 0];
            g1 += h * W2[2 * f + 1];
        }
        g[n] = make_float2(g0, g1);
    }
}
__global__ void agg2_kernel(const int* __restrict__ src, const int* __restrict__ dst,
                            const float* __restrict__ w, const float* __restrict__ dinv,
                            const float2* __restrict__ g, float* __restrict__ agg, int E) {
    int e = blockIdx.x * blockDim.x + threadIdx.x;
    if (e < E) {
        int si = src[e], di = dst[e];
        float norm = dinv[si] * w[e] * dinv[di];
        float2 gv = g[si];
        atomicAdd(&agg[2 * di + 0], norm * gv.x);
        atomicAdd(&agg[2 * di + 1], norm * gv.y);
    }
}
__global__ void out_kernel(float* __restrict__ out, const float* __restrict__ dinv,
                           const float2* __restrict__ g, const float* __restrict__ b2, int N) {
    int n = blockIdx.x * blockDim.x + threadIdx.x;
    if (n < N) {
        float dv2 = dinv[n] * dinv[n];
        float2 gv = g[n];
        float a0 = out[2 * n + 0] + dv2 * gv.x + b2[0];
        float a1 = out[2 * n + 1] + dv2 * gv.y + b2[1];
        float m = fmaxf(a0, a1);
        float lse = m + logf(expf(a0 - m) + expf(a1 - m));
        out[2 * n + 0] = a0 - lse;
        out[2 * n + 1] = a1 - lse;
    }
}

// ======================= launch =======================

extern "C" void kernel_launch(void* const* d_in, const int* in_sizes, int n_in,
                              void* d_out, int out_size, void* d_ws, size_t ws_size,
                              hipStream_t stream) {
    const float* x  = (const float*)d_in[0];
    const int*   ei = (const int*)d_in[1];     // [2, E] delivered as int32
    const float* w  = (const float*)d_in[2];
    const float* W1 = (const float*)d_in[3];
    const float* b1 = (const float*)d_in[4];
    const float* W2 = (const float*)d_in[5];
    const float* b2 = (const float*)d_in[6];
    float* out = (float*)d_out;

    const int N = in_sizes[0];
    const int E = in_sizes[2];
    const int* src = ei;
    const int* dst = ei + E;

    const int NB = (N + CHUNK - 1) / CHUNK;    // 782 for N=100000

    // ws layout for sorted path (8-byte payload first for alignment)
    size_t off = 0;
    size_t payload_off = off;            off += (size_t)E * 8;
    size_t cnt_off     = off;            off += (size_t)NB * 4;
    size_t start_off   = off;            off += (size_t)(NB + 1) * 4;
    size_t cursor_off  = off;            off += (size_t)NB * 4;
    off = (off + 7) & ~(size_t)7;
    size_t dinv_off    = off;            off += (size_t)N * 4;
    size_t gamma_off   = off;            off += (size_t)N * 4;
    const size_t required = off;

    if (NB <= MAXNB && ws_size >= required) {
        char* wsb = (char*)d_ws;
        unsigned long long* payload = (unsigned long long*)(wsb + payload_off);
        unsigned int* cnt    = (unsigned int*)(wsb + cnt_off);
        unsigned int* startp = (unsigned int*)(wsb + start_off);
        unsigned int* cursor = (unsigned int*)(wsb + cursor_off);
        float* dinv  = (float*)(wsb + dinv_off);
        float* gamma = (float*)(wsb + gamma_off);

        const int gridSort = (E + EPB - 1) / EPB;

        zero_counts_kernel<<<(NB + BLOCK - 1) / BLOCK, BLOCK, 0, stream>>>(cnt, NB);
        hist_kernel    <<<gridSort, BLOCK, 0, stream>>>(dst, cnt, E, NB);
        scan_kernel    <<<1, MAXNB, 0, stream>>>(cnt, startp, cursor, NB);
        scatter_kernel <<<gridSort, BLOCK, 0, stream>>>(src, dst, w, cursor, payload, E, NB);
        deg_dinv_kernel<<<NB, BLOCK, 0, stream>>>(payload, startp, dinv, N);
        s_gamma_kernel <<<NB, BLOCK, 0, stream>>>(payload, startp, dinv, x, W1, b1, W2, gamma, N);
        d_out_kernel   <<<NB, BLOCK, 0, stream>>>(payload, startp, dinv, gamma, b2, out, N);
    } else {
        // R3 fallback: global-atomic path (needs 4N floats of ws)
        float*  ws   = (float*)d_ws;
        float*  dinv = ws;
        float*  s    = ws + (size_t)N;
        float2* g    = (float2*)(ws + (size_t)2 * N);
        const int gridE  = (E + BLOCK - 1) / BLOCK;
        const int gridN  = (N + BLOCK - 1) / BLOCK;
        const int gridN2 = (2 * N + BLOCK - 1) / BLOCK;
        zero_kernel<<<gridN2, BLOCK, 0, stream>>>(ws, out, 2 * N);
        deg_kernel <<<gridE,  BLOCK, 0, stream>>>(dst, w, dinv, E);
        dinv_kernel<<<gridN,  BLOCK, 0, stream>>>(dinv, N);
        s_kernel   <<<gridE,  BLOCK, 0, stream>>>(src, dst, w, dinv, x, s, E);
        g_kernel   <<<gridN,  BLOCK, 0, stream>>>(s, dinv, x, W1, b1, W2, g, N);
        agg2_kernel<<<gridE,  BLOCK, 0, stream>>>(src, dst, w, dinv, g, out, E);
        out_kernel <<<gridN,  BLOCK, 0, stream>>>(out, dinv, g, b2, N);
    }
}

// Round 5
// 235.222 us; speedup vs baseline: 3.1457x; 1.0862x over previous
//
#include <hip/hip_runtime.h>
#include <math.h>

// GCN 2-layer, N=100K, E=3.2M, feat 1->16->2, log_softmax.
//
// R4 lesson (rocprof): globally-scattered 8B payload writes amplify 3.3x at
// HBM (84 MB WRITE_SIZE vs 26 MB ideal) because L2 lines evict part-filled.
// R5: block-LOCAL counting sort. Each block writes its 8192 edges grouped by
// bucket into its OWN contiguous 64 KB region (random only within region ->
// L2 write-back assembles full lines -> no amplification), plus a per-block
// CSR row rowOff[blk][bucket]. No global atomics at all; hist/scan pre-passes
// eliminated. Aggregation kernels walk a bucket as nblk short runs via LDS
// run descriptors + binary search; payload reads are L3-resident.
// 2-class log_softmax needs only d = a1-a0 => layer 2 uses scalar gamma.

static constexpr int BLOCK_S   = 512;   // scatter threads
static constexpr int EPB       = 8192;  // edges per scatter block (64 KB region)
static constexpr int CHUNK     = 256;   // nodes per bucket (pow2)
static constexpr int LOG_CHUNK = 8;
static constexpr int BLOCK_A   = 512;   // aggregation threads
static constexpr int MAXNB     = 512;   // max buckets   (N <= 131072)
static constexpr int MAXBLK    = 512;   // max scatter blocks (E <= 4.19M)

// ======================= sorted path =======================

__global__ __launch_bounds__(BLOCK_S) void scatter_kernel(
    const int* __restrict__ src, const int* __restrict__ dst,
    const float* __restrict__ w,
    unsigned int* __restrict__ rowOff,         // [nblk][nb+1]
    unsigned long long* __restrict__ payload,  // [nblk*EPB]
    int E, int nb) {
    __shared__ unsigned int hist[MAXNB];
    __shared__ unsigned int cursor[MAXNB];
    const int blk  = blockIdx.x;
    const int base = blk * EPB;
    const int nE   = min(EPB, E - base);
    const int t    = threadIdx.x;
    if (t < nb) hist[t] = 0u;
    __syncthreads();
    for (int k = t; k < nE; k += BLOCK_S)
        atomicAdd(&hist[(unsigned int)dst[base + k] >> LOG_CHUNK], 1u);
    __syncthreads();
    unsigned int val = (t < nb) ? hist[t] : 0u;
    // Hillis-Steele inclusive scan of hist[0..nb)
    for (int off = 1; off < MAXNB; off <<= 1) {
        unsigned int v = (t >= off && t < nb) ? hist[t - off] : 0u;
        __syncthreads();
        if (t < nb) hist[t] += v;
        __syncthreads();
    }
    if (t < nb) {
        unsigned int excl = hist[t] - val;     // exclusive prefix
        cursor[t] = excl;
        rowOff[(size_t)blk * (nb + 1) + t] = excl;
    }
    if (t == 0) rowOff[(size_t)blk * (nb + 1) + nb] = (unsigned int)nE;
    __syncthreads();
    for (int k = t; k < nE; k += BLOCK_S) {
        int e = base + k;
        int d = dst[e];
        int b = (unsigned int)d >> LOG_CHUNK;
        unsigned int slot = atomicAdd(&cursor[b], 1u);   // LDS atomic
        unsigned long long p =
            ((unsigned long long)__float_as_uint(w[e]) << 32) |
            ((unsigned int)src[e] << LOG_CHUNK) |
            (unsigned int)(d & (CHUNK - 1));
        payload[(size_t)base + slot] = p;                // within-region write
    }
}

// Shared bucket-walk prologue (run descriptors -> cumx/radj + total) is
// replicated in each aggregation kernel below.

__global__ __launch_bounds__(BLOCK_A) void deg_dinv_kernel(
    const unsigned long long* __restrict__ payload,
    const unsigned int* __restrict__ rowOff,
    float* __restrict__ dinv, int N, int nb, int nblk) {
    __shared__ int          radj[MAXBLK];
    __shared__ unsigned int sc[MAXBLK];
    __shared__ unsigned int cumx[MAXBLK];
    __shared__ float        acc[CHUNK];
    __shared__ unsigned int totsh;
    const int b = blockIdx.x, t = threadIdx.x;
    if (t < CHUNK) acc[t] = 0.0f;
    unsigned int len = 0, s0 = 0;
    if (t < nblk) {
        s0  = rowOff[(size_t)t * (nb + 1) + b];
        len = rowOff[(size_t)t * (nb + 1) + b + 1] - s0;
    }
    sc[t] = len;
    __syncthreads();
    for (int off = 1; off < MAXBLK; off <<= 1) {
        unsigned int v = (t >= off) ? sc[t - off] : 0u;
        __syncthreads();
        sc[t] += v;
        __syncthreads();
    }
    if (t < nblk) {
        unsigned int ex = sc[t] - len;
        cumx[t] = ex;
        radj[t] = (int)s0 - (int)ex + t * EPB;  // payload idx = radj[r] + i
    }
    if (t == nblk - 1) totsh = sc[t];
    __syncthreads();
    const unsigned int total = totsh;
    for (unsigned int i = t; i < total; i += BLOCK_A) {
        int lo = 0, hi = nblk - 1;
        while (lo < hi) {
            int mid = (lo + hi + 1) >> 1;
            if (cumx[mid] <= i) lo = mid; else hi = mid - 1;
        }
        unsigned long long p = payload[(unsigned int)(radj[lo] + (int)i)];
        float wv = __uint_as_float((unsigned int)(p >> 32));
        atomicAdd(&acc[(unsigned int)p & (CHUNK - 1)], wv);
    }
    __syncthreads();
    int n = b * CHUNK + t;
    if (t < CHUNK && n < N) {
        float d = acc[t] + 1.0f;                 // self-loop fill 1.0
        dinv[n] = (d > 0.0f) ? rsqrtf(d) : 0.0f;
    }
}

__global__ __launch_bounds__(BLOCK_A) void s_gamma_kernel(
    const unsigned long long* __restrict__ payload,
    const unsigned int* __restrict__ rowOff,
    const float* __restrict__ dinv,
    const float* __restrict__ x,
    const float* __restrict__ W1,    // [16]
    const float* __restrict__ b1,    // [16]
    const float* __restrict__ W2,    // [16][2]
    float* __restrict__ gamma, int N, int nb, int nblk) {
    __shared__ int          radj[MAXBLK];
    __shared__ unsigned int sc[MAXBLK];
    __shared__ unsigned int cumx[MAXBLK];
    __shared__ float        acc[CHUNK];
    __shared__ float        dloc[CHUNK];
    __shared__ unsigned int totsh;
    const int b = blockIdx.x, t = threadIdx.x;
    if (t < CHUNK) {
        acc[t] = 0.0f;
        int n = b * CHUNK + t;
        dloc[t] = (n < N) ? dinv[n] : 0.0f;
    }
    unsigned int len = 0, s0 = 0;
    if (t < nblk) {
        s0  = rowOff[(size_t)t * (nb + 1) + b];
        len = rowOff[(size_t)t * (nb + 1) + b + 1] - s0;
    }
    sc[t] = len;
    __syncthreads();
    for (int off = 1; off < MAXBLK; off <<= 1) {
        unsigned int v = (t >= off) ? sc[t - off] : 0u;
        __syncthreads();
        sc[t] += v;
        __syncthreads();
    }
    if (t < nblk) {
        unsigned int ex = sc[t] - len;
        cumx[t] = ex;
        radj[t] = (int)s0 - (int)ex + t * EPB;
    }
    if (t == nblk - 1) totsh = sc[t];
    __syncthreads();
    const unsigned int total = totsh;
    for (unsigned int i = t; i < total; i += BLOCK_A) {
        int lo = 0, hi = nblk - 1;
        while (lo < hi) {
            int mid = (lo + hi + 1) >> 1;
            if (cumx[mid] <= i) lo = mid; else hi = mid - 1;
        }
        unsigned long long p = payload[(unsigned int)(radj[lo] + (int)i)];
        float wv = __uint_as_float((unsigned int)(p >> 32));
        unsigned int lo32 = (unsigned int)p;
        int si = (int)(lo32 >> LOG_CHUNK);
        int dl = (int)(lo32 & (CHUNK - 1));
        float norm = dinv[si] * wv * dloc[dl];
        atomicAdd(&acc[dl], norm * x[si]);
    }
    __syncthreads();
    int n = b * CHUNK + t;
    if (t < CHUNK && n < N) {
        float dv = dloc[t];
        float sv = acc[t] + dv * dv * x[n];      // + self-loop msg
        float gd = 0.0f;
#pragma unroll
        for (int f = 0; f < 16; ++f) {
            float h = fmaxf(sv * W1[f] + b1[f], 0.0f);    // relu(layer1)
            gd += h * (W2[2 * f + 1] - W2[2 * f + 0]);    // g1 - g0
        }
        gamma[n] = gd;
    }
}

__global__ __launch_bounds__(BLOCK_A) void d_out_kernel(
    const unsigned long long* __restrict__ payload,
    const unsigned int* __restrict__ rowOff,
    const float* __restrict__ dinv,
    const float* __restrict__ gamma,
    const float* __restrict__ b2,    // [2]
    float* __restrict__ out, int N, int nb, int nblk) {
    __shared__ int          radj[MAXBLK];
    __shared__ unsigned int sc[MAXBLK];
    __shared__ unsigned int cumx[MAXBLK];
    __shared__ float        acc[CHUNK];
    __shared__ float        dloc[CHUNK];
    __shared__ unsigned int totsh;
    const int b = blockIdx.x, t = threadIdx.x;
    if (t < CHUNK) {
        acc[t] = 0.0f;
        int n = b * CHUNK + t;
        dloc[t] = (n < N) ? dinv[n] : 0.0f;
    }
    unsigned int len = 0, s0 = 0;
    if (t < nblk) {
        s0  = rowOff[(size_t)t * (nb + 1) + b];
        len = rowOff[(size_t)t * (nb + 1) + b + 1] - s0;
    }
    sc[t] = len;
    __syncthreads();
    for (int off = 1; off < MAXBLK; off <<= 1) {
        unsigned int v = (t >= off) ? sc[t - off] : 0u;
        __syncthreads();
        sc[t] += v;
        __syncthreads();
    }
    if (t < nblk) {
        unsigned int ex = sc[t] - len;
        cumx[t] = ex;
        radj[t] = (int)s0 - (int)ex + t * EPB;
    }
    if (t == nblk - 1) totsh = sc[t];
    __syncthreads();
    const unsigned int total = totsh;
    for (unsigned int i = t; i < total; i += BLOCK_A) {
        int lo = 0, hi = nblk - 1;
        while (lo < hi) {
            int mid = (lo + hi + 1) >> 1;
            if (cumx[mid] <= i) lo = mid; else hi = mid - 1;
        }
        unsigned long long p = payload[(unsigned int)(radj[lo] + (int)i)];
        float wv = __uint_as_float((unsigned int)(p >> 32));
        unsigned int lo32 = (unsigned int)p;
        int si = (int)(lo32 >> LOG_CHUNK);
        int dl = (int)(lo32 & (CHUNK - 1));
        float norm = dinv[si] * wv * dloc[dl];
        atomicAdd(&acc[dl], norm * gamma[si]);
    }
    __syncthreads();
    int n = b * CHUNK + t;
    if (t < CHUNK && n < N) {
        float dv = dloc[t];
        float d = acc[t] + dv * dv * gamma[n] + (b2[1] - b2[0]);
        // 2-class log_softmax from d = a1 - a0 (stable)
        float lse = fmaxf(d, 0.0f) + log1pf(expf(-fabsf(d)));
        out[2 * n + 0] = -lse;
        out[2 * n + 1] = d - lse;
    }
}

// ======================= fallback: R3 global-atomic path =======================

static constexpr int BLOCK = 256;

__global__ void zero_kernel(float* __restrict__ a, float* __restrict__ b, int n2) {
    int i = blockIdx.x * blockDim.x + threadIdx.x;
    if (i < n2) { a[i] = 0.0f; b[i] = 0.0f; }
}
__global__ void deg_kernel(const int* __restrict__ dst, const float* __restrict__ w,
                           float* __restrict__ deg, int E) {
    int e = blockIdx.x * blockDim.x + threadIdx.x;
    if (e < E) atomicAdd(&deg[dst[e]], w[e]);
}
__global__ void dinv_kernel(float* __restrict__ deg, int N) {
    int n = blockIdx.x * blockDim.x + threadIdx.x;
    if (n < N) {
        float d = deg[n] + 1.0f;
        deg[n] = (d > 0.0f) ? rsqrtf(d) : 0.0f;
    }
}
__global__ void s_kernel(const int* __restrict__ src, const int* __restrict__ dst,
                         const float* __restrict__ w, const float* __restrict__ dinv,
                         const float* __restrict__ x, float* __restrict__ s, int E) {
    int e = blockIdx.x * blockDim.x + threadIdx.x;
    if (e < E) {
        int si = src[e], di = dst[e];
        atomicAdd(&s[di], dinv[si] * w[e] * dinv[di] * x[si]);
    }
}
__global__ void g_kernel(const float* __restrict__ s, const float* __restrict__ dinv,
                         const float* __restrict__ x, const float* __restrict__ W1,
                         const float* __restrict__ b1, const float* __restrict__ W2,
                         float2* __restrict__ g, int N) {
    int n = blockIdx.x * blockDim.x + threadIdx.x;
    if (n < N) {
        float dv = dinv[n];
        float sv = s[n] + dv * dv * x[n];
        float g0 = 0.0f, g1 = 0.0f;
#pragma unroll
        for (int f = 0; f < 16; ++f) {
            float h = fmaxf(sv * W1[f] + b1[f], 0.0f);
            g0 += h * W2[2 * f + 0];
            g1 += h * W2[2 * f + 1];
        }
        g[n] = make_float2(g0, g1);
    }
}
__global__ void agg2_kernel(const int* __restrict__ src, const int* __restrict__ dst,
                            const float* __restrict__ w, const float* __restrict__ dinv,
                            const float2* __restrict__ g, float* __restrict__ agg, int E) {
    int e = blockIdx.x * blockDim.x + threadIdx.x;
    if (e < E) {
        int si = src[e], di = dst[e];
        float norm = dinv[si] * w[e] * dinv[di];
        float2 gv = g[si];
        atomicAdd(&agg[2 * di + 0], norm * gv.x);
        atomicAdd(&agg[2 * di + 1], norm * gv.y);
    }
}
__global__ void out_kernel(float* __restrict__ out, const float* __restrict__ dinv,
                           const float2* __restrict__ g, const float* __restrict__ b2, int N) {
    int n = blockIdx.x * blockDim.x + threadIdx.x;
    if (n < N) {
        float dv2 = dinv[n] * dinv[n];
        float2 gv = g[n];
        float a0 = out[2 * n + 0] + dv2 * gv.x + b2[0];
        float a1 = out[2 * n + 1] + dv2 * gv.y + b2[1];
        float m = fmaxf(a0, a1);
        float lse = m + logf(expf(a0 - m) + expf(a1 - m));
        out[2 * n + 0] = a0 - lse;
        out[2 * n + 1] = a1 - lse;
    }
}

// ======================= launch =======================

extern "C" void kernel_launch(void* const* d_in, const int* in_sizes, int n_in,
                              void* d_out, int out_size, void* d_ws, size_t ws_size,
                              hipStream_t stream) {
    const float* x  = (const float*)d_in[0];
    const int*   ei = (const int*)d_in[1];     // [2, E] delivered as int32
    const float* w  = (const float*)d_in[2];
    const float* W1 = (const float*)d_in[3];
    const float* b1 = (const float*)d_in[4];
    const float* W2 = (const float*)d_in[5];
    const float* b2 = (const float*)d_in[6];
    float* out = (float*)d_out;

    const int N = in_sizes[0];
    const int E = in_sizes[2];
    const int* src = ei;
    const int* dst = ei + E;

    const int nb   = (N + CHUNK - 1) / CHUNK;   // 391
    const int nblk = (E + EPB - 1) / EPB;       // 391

    // ws layout: payload | rowOff | dinv | gamma
    size_t off = 0;
    size_t payload_off = off;  off += (size_t)nblk * EPB * 8;
    size_t rowoff_off  = off;  off += (size_t)nblk * (nb + 1) * 4;
    off = (off + 7) & ~(size_t)7;
    size_t dinv_off    = off;  off += (size_t)N * 4;
    size_t gamma_off   = off;  off += (size_t)N * 4;
    const size_t required = off;

    if (nb <= MAXNB && nblk <= MAXBLK && ws_size >= required) {
        char* wsb = (char*)d_ws;
        unsigned long long* payload = (unsigned long long*)(wsb + payload_off);
        unsigned int* rowOff = (unsigned int*)(wsb + rowoff_off);
        float* dinv  = (float*)(wsb + dinv_off);
        float* gamma = (float*)(wsb + gamma_off);

        scatter_kernel <<<nblk, BLOCK_S, 0, stream>>>(src, dst, w, rowOff, payload, E, nb);
        deg_dinv_kernel<<<nb,   BLOCK_A, 0, stream>>>(payload, rowOff, dinv, N, nb, nblk);
        s_gamma_kernel <<<nb,   BLOCK_A, 0, stream>>>(payload, rowOff, dinv, x, W1, b1, W2,
                                                      gamma, N, nb, nblk);
        d_out_kernel   <<<nb,   BLOCK_A, 0, stream>>>(payload, rowOff, dinv, gamma, b2,
                                                      out, N, nb, nblk);
    } else {
        // R3 fallback: global-atomic path (needs 4N floats of ws)
        float*  ws   = (float*)d_ws;
        float*  dinv = ws;
        float*  s    = ws + (size_t)N;
        float2* g    = (float2*)(ws + (size_t)2 * N);
        const int gridE  = (E + BLOCK - 1) / BLOCK;
        const int gridN  = (N + BLOCK - 1) / BLOCK;
        const int gridN2 = (2 * N + BLOCK - 1) / BLOCK;
        zero_kernel<<<gridN2, BLOCK, 0, stream>>>(ws, out, 2 * N);
        deg_kernel <<<gridE,  BLOCK, 0, stream>>>(dst, w, dinv, E);
        dinv_kernel<<<gridN,  BLOCK, 0, stream>>>(dinv, N);
        s_kernel   <<<gridE,  BLOCK, 0, stream>>>(src, dst, w, dinv, x, s, E);
        g_kernel   <<<gridN,  BLOCK, 0, stream>>>(s, dinv, x, W1, b1, W2, g, N);
        agg2_kernel<<<gridE,  BLOCK, 0, stream>>>(src, dst, w, dinv, g, out, E);
        out_kernel <<<gridN,  BLOCK, 0, stream>>>(out, dinv, g, b2, N);
    }
}

// Round 6
// 186.632 us; speedup vs baseline: 3.9647x; 1.2604x over previous
//
#include <hip/hip_runtime.h>
#include <math.h>

// GCN 2-layer, N=100K, E=3.2M, feat 1->16->2, log_softmax.
//
// R5 lessons (rocprof): (1) random-order 8B writes even into a private 64 KB
// region still amplify ~2.8x at HBM (too many active regions per 4MB XCD L2
// -> lines evict part-filled). Fix: sort tile in LDS, stream out coalesced.
// (2) Aggregation per-edge binary search = 9 DEPENDENT ds_reads (~120cy each)
// -> replace with a once-per-block LDS run-offset table (1 ds_read/edge).
// (3) Halve random gathers: precompute xd = dinv*x, gd = dinv*gamma; factor
// dinv[dst] out of the per-edge sum into the epilogue.
//
// 2-class log_softmax needs only d = a1-a0 => layer 2 uses scalar gd.

static constexpr int BLOCK_S   = 512;    // scatter threads (== MAXNB)
static constexpr int EPB       = 7936;   // edges per scatter tile (62 KB LDS)
static constexpr int CHUNK     = 256;    // nodes per bucket (pow2)
static constexpr int LOG_CHUNK = 8;
static constexpr int BLOCK_A   = 1024;   // aggregation threads
static constexpr int MAXNB     = 512;    // max buckets (N <= 131072)
static constexpr int MAXBLK    = 512;    // max scatter tiles (E <= 4.06M)
static constexpr int TABCAP    = 10240;  // run-table entries (bucket size bound)

// ======================= scatter: LDS sort + coalesced write-out =======================

__global__ __launch_bounds__(BLOCK_S) void scatter_kernel(
    const int* __restrict__ src, const int* __restrict__ dst,
    const float* __restrict__ w,
    unsigned int* __restrict__ rowOff,         // [nblk][nb+1]
    unsigned long long* __restrict__ payload,  // [nblk*EPB]
    int E, int nb) {
    __shared__ unsigned long long pbuf[EPB];   // 63488 B staging
    __shared__ unsigned int hist[MAXNB];       // 2048 B (reused as cursor)
    const int blk  = blockIdx.x;
    const int base = blk * EPB;
    const int nE   = min(EPB, E - base);
    const int t    = threadIdx.x;

    hist[t] = 0u;
    __syncthreads();

    int dc[16];                                 // per-thread dst cache
    int cnt = 0;
    for (int k = t; k < nE; k += BLOCK_S) {
        int d = dst[base + k];
        dc[cnt++] = d;
        atomicAdd(&hist[(unsigned int)d >> LOG_CHUNK], 1u);
    }
    __syncthreads();

    unsigned int val = hist[t];
    // Hillis-Steele inclusive scan over hist[0..MAXNB)
    for (int off = 1; off < MAXNB; off <<= 1) {
        unsigned int v = (t >= off) ? hist[t - off] : 0u;
        __syncthreads();
        hist[t] += v;
        __syncthreads();
    }
    unsigned int excl = hist[t] - val;
    if (t < nb) rowOff[(size_t)blk * (nb + 1) + t] = excl;
    if (t == 0) rowOff[(size_t)blk * (nb + 1) + nb] = (unsigned int)nE;
    __syncthreads();
    hist[t] = excl;                             // -> cursor
    __syncthreads();

    cnt = 0;
    for (int k = t; k < nE; k += BLOCK_S) {
        int d = dc[cnt++];
        int b = (unsigned int)d >> LOG_CHUNK;
        unsigned int slot = atomicAdd(&hist[b], 1u);     // LDS atomic
        unsigned long long p =
            ((unsigned long long)__float_as_uint(w[base + k]) << 32) |
            ((unsigned int)src[base + k] << LOG_CHUNK) |
            (unsigned int)(d & (CHUNK - 1));
        pbuf[slot] = p;                                  // random LDS write
    }
    __syncthreads();
    // coalesced, in-order global write-out: full lines, no amplification
    for (int k = t; k < nE; k += BLOCK_S)
        payload[(size_t)base + k] = pbuf[k];
}

// ======================= aggregation kernels =======================
// Common prologue: per-block scan of this bucket's run lengths across all
// tiles -> cumx/radj; then a run-offset table so the per-edge cost is one
// independent ds_read instead of a dependent binary search.

#define AGG_PROLOGUE                                                          \
    const int b = blockIdx.x, t = threadIdx.x;                                \
    unsigned int len = 0, s0 = 0;                                             \
    if (t < MAXBLK) {                                                         \
        if (t < nblk) {                                                       \
            s0  = rowOff[(size_t)t * (nb + 1) + b];                           \
            len = rowOff[(size_t)t * (nb + 1) + b + 1] - s0;                  \
        }                                                                     \
        sc[t] = len;                                                          \
    }                                                                         \
    __syncthreads();                                                          \
    for (int off = 1; off < MAXBLK; off <<= 1) {                              \
        unsigned int v = 0;                                                   \
        if (t < MAXBLK && t >= off) v = sc[t - off];                          \
        __syncthreads();                                                      \
        if (t < MAXBLK) sc[t] += v;                                           \
        __syncthreads();                                                      \
    }                                                                         \
    if (t < nblk) {                                                           \
        unsigned int ex = sc[t] - len;                                        \
        cumx[t] = ex;                                                         \
        radj[t] = (int)s0 - (int)ex + t * EPB;                                \
    }                                                                         \
    if (t == nblk - 1) totsh = sc[t];                                         \
    __syncthreads();                                                          \
    const unsigned int total = totsh;                                         \
    if (t < nblk) {                                                           \
        unsigned int beg = cumx[t];                                           \
        unsigned int end = (t == nblk - 1) ? total : cumx[t + 1];             \
        unsigned int lim = min(end, (unsigned int)TABCAP);                    \
        int a = radj[t];                                                      \
        for (unsigned int i = beg; i < lim; ++i) table[i] = a;                \
    }                                                                         \
    __syncthreads();

__device__ __forceinline__ int run_adj_fallback(const unsigned int* cumx,
                                                const int* radj,
                                                unsigned int i, int nblk) {
    int lo = 0, hi = nblk - 1;
    while (lo < hi) {
        int mid = (lo + hi + 1) >> 1;
        if (cumx[mid] <= i) lo = mid; else hi = mid - 1;
    }
    return radj[lo];
}

__global__ __launch_bounds__(BLOCK_A) void deg_dinv_kernel(
    const unsigned long long* __restrict__ payload,
    const unsigned int* __restrict__ rowOff,
    const float* __restrict__ x,
    float* __restrict__ dinv, float* __restrict__ xd,
    int N, int nb, int nblk) {
    __shared__ unsigned int sc[MAXBLK];
    __shared__ unsigned int cumx[MAXBLK];
    __shared__ int          radj[MAXBLK];
    __shared__ float        acc[CHUNK];
    __shared__ int          table[TABCAP];
    __shared__ unsigned int totsh;
    if (threadIdx.x < CHUNK) acc[threadIdx.x] = 0.0f;
    AGG_PROLOGUE
    for (unsigned int i = t; i < total; i += BLOCK_A) {
        int adj = (i < TABCAP) ? table[i] : run_adj_fallback(cumx, radj, i, nblk);
        unsigned long long p = payload[(unsigned int)(adj + (int)i)];
        float wv = __uint_as_float((unsigned int)(p >> 32));
        atomicAdd(&acc[(unsigned int)p & (CHUNK - 1)], wv);
    }
    __syncthreads();
    int n = b * CHUNK + t;
    if (t < CHUNK && n < N) {
        float d = acc[t] + 1.0f;                  // self-loop fill 1.0
        float r = (d > 0.0f) ? rsqrtf(d) : 0.0f;
        dinv[n] = r;
        xd[n]   = r * x[n];
    }
}

__global__ __launch_bounds__(BLOCK_A) void s_gamma_kernel(
    const unsigned long long* __restrict__ payload,
    const unsigned int* __restrict__ rowOff,
    const float* __restrict__ dinv,
    const float* __restrict__ xd,
    const float* __restrict__ W1,    // [16]
    const float* __restrict__ b1,    // [16]
    const float* __restrict__ W2,    // [16][2]
    float* __restrict__ gd, int N, int nb, int nblk) {
    __shared__ unsigned int sc[MAXBLK];
    __shared__ unsigned int cumx[MAXBLK];
    __shared__ int          radj[MAXBLK];
    __shared__ float        acc[CHUNK];
    __shared__ int          table[TABCAP];
    __shared__ unsigned int totsh;
    if (threadIdx.x < CHUNK) acc[threadIdx.x] = 0.0f;
    AGG_PROLOGUE
    for (unsigned int i = t; i < total; i += BLOCK_A) {
        int adj = (i < TABCAP) ? table[i] : run_adj_fallback(cumx, radj, i, nblk);
        unsigned long long p = payload[(unsigned int)(adj + (int)i)];
        float wv = __uint_as_float((unsigned int)(p >> 32));
        unsigned int lo32 = (unsigned int)p;
        int si = (int)(lo32 >> LOG_CHUNK);
        atomicAdd(&acc[lo32 & (CHUNK - 1)], wv * xd[si]);   // dinv[dst] factored out
    }
    __syncthreads();
    int n = b * CHUNK + t;
    if (t < CHUNK && n < N) {
        float dv = dinv[n];
        float sv = dv * (acc[t] + xd[n]);         // + self-loop dv*dv*x[n]
        float g = 0.0f;
#pragma unroll
        for (int f = 0; f < 16; ++f) {
            float h = fmaxf(sv * W1[f] + b1[f], 0.0f);      // relu(layer1)
            g += h * (W2[2 * f + 1] - W2[2 * f + 0]);       // gamma = g1-g0
        }
        gd[n] = dv * g;                           // pre-scaled for layer 2
    }
}

__global__ __launch_bounds__(BLOCK_A) void d_out_kernel(
    const unsigned long long* __restrict__ payload,
    const unsigned int* __restrict__ rowOff,
    const float* __restrict__ dinv,
    const float* __restrict__ gd,
    const float* __restrict__ b2,    // [2]
    float* __restrict__ out, int N, int nb, int nblk) {
    __shared__ unsigned int sc[MAXBLK];
    __shared__ unsigned int cumx[MAXBLK];
    __shared__ int          radj[MAXBLK];
    __shared__ float        acc[CHUNK];
    __shared__ int          table[TABCAP];
    __shared__ unsigned int totsh;
    if (threadIdx.x < CHUNK) acc[threadIdx.x] = 0.0f;
    AGG_PROLOGUE
    for (unsigned int i = t; i < total; i += BLOCK_A) {
        int adj = (i < TABCAP) ? table[i] : run_adj_fallback(cumx, radj, i, nblk);
        unsigned long long p = payload[(unsigned int)(adj + (int)i)];
        float wv = __uint_as_float((unsigned int)(p >> 32));
        unsigned int lo32 = (unsigned int)p;
        int si = (int)(lo32 >> LOG_CHUNK);
        atomicAdd(&acc[lo32 & (CHUNK - 1)], wv * gd[si]);
    }
    __syncthreads();
    int n = b * CHUNK + t;
    if (t < CHUNK && n < N) {
        float dv = dinv[n];
        float d = dv * (acc[t] + gd[n]) + (b2[1] - b2[0]);
        // 2-class log_softmax from d = a1 - a0 (stable)
        float lse = fmaxf(d, 0.0f) + log1pf(expf(-fabsf(d)));
        out[2 * n + 0] = -lse;
        out[2 * n + 1] = d - lse;
    }
}

// ======================= fallback: R3 global-atomic path =======================

static constexpr int BLOCK = 256;

__global__ void zero_kernel(float* __restrict__ a, float* __restrict__ b, int n2) {
    int i = blockIdx.x * blockDim.x + threadIdx.x;
    if (i < n2) { a[i] = 0.0f; b[i] = 0.0f; }
}
__global__ void deg_kernel(const int* __restrict__ dst, const float* __restrict__ w,
                           float* __restrict__ deg, int E) {
    int e = blockIdx.x * blockDim.x + threadIdx.x;
    if (e < E) atomicAdd(&deg[dst[e]], w[e]);
}
__global__ void dinv_kernel(float* __restrict__ deg, int N) {
    int n = blockIdx.x * blockDim.x + threadIdx.x;
    if (n < N) {
        float d = deg[n] + 1.0f;
        deg[n] = (d > 0.0f) ? rsqrtf(d) : 0.0f;
    }
}
__global__ void s_kernel(const int* __restrict__ src, const int* __restrict__ dst,
                         const float* __restrict__ w, const float* __restrict__ dinv,
                         const float* __restrict__ x, float* __restrict__ s, int E) {
    int e = blockIdx.x * blockDim.x + threadIdx.x;
    if (e < E) {
        int si = src[e], di = dst[e];
        atomicAdd(&s[di], dinv[si] * w[e] * dinv[di] * x[si]);
    }
}
__global__ void g_kernel(const float* __restrict__ s, const float* __restrict__ dinv,
                         const float* __restrict__ x, const float* __restrict__ W1,
                         const float* __restrict__ b1, const float* __restrict__ W2,
                         float2* __restrict__ g, int N) {
    int n = blockIdx.x * blockDim.x + threadIdx.x;
    if (n < N) {
        float dv = dinv[n];
        float sv = s[n] + dv * dv * x[n];
        float g0 = 0.0f, g1 = 0.0f;
#pragma unroll
        for (int f = 0; f < 16; ++f) {
            float h = fmaxf(sv * W1[f] + b1[f], 0.0f);
            g0 += h * W2[2 * f + 0];
            g1 += h * W2[2 * f + 1];
        }
        g[n] = make_float2(g0, g1);
    }
}
__global__ void agg2_kernel(const int* __restrict__ src, const int* __restrict__ dst,
                            const float* __restrict__ w, const float* __restrict__ dinv,
                            const float2* __restrict__ g, float* __restrict__ agg, int E) {
    int e = blockIdx.x * blockDim.x + threadIdx.x;
    if (e < E) {
        int si = src[e], di = dst[e];
        float norm = dinv[si] * w[e] * dinv[di];
        float2 gv = g[si];
        atomicAdd(&agg[2 * di + 0], norm * gv.x);
        atomicAdd(&agg[2 * di + 1], norm * gv.y);
    }
}
__global__ void out_kernel(float* __restrict__ out, const float* __restrict__ dinv,
                           const float2* __restrict__ g, const float* __restrict__ b2, int N) {
    int n = blockIdx.x * blockDim.x + threadIdx.x;
    if (n < N) {
        float dv2 = dinv[n] * dinv[n];
        float2 gv = g[n];
        float a0 = out[2 * n + 0] + dv2 * gv.x + b2[0];
        float a1 = out[2 * n + 1] + dv2 * gv.y + b2[1];
        float m = fmaxf(a0, a1);
        float lse = m + logf(expf(a0 - m) + expf(a1 - m));
        out[2 * n + 0] = a0 - lse;
        out[2 * n + 1] = a1 - lse;
    }
}

// ======================= launch =======================

extern "C" void kernel_launch(void* const* d_in, const int* in_sizes, int n_in,
                              void* d_out, int out_size, void* d_ws, size_t ws_size,
                              hipStream_t stream) {
    const float* x  = (const float*)d_in[0];
    const int*   ei = (const int*)d_in[1];     // [2, E] delivered as int32
    const float* w  = (const float*)d_in[2];
    const float* W1 = (const float*)d_in[3];
    const float* b1 = (const float*)d_in[4];
    const float* W2 = (const float*)d_in[5];
    const float* b2 = (const float*)d_in[6];
    float* out = (float*)d_out;

    const int N = in_sizes[0];
    const int E = in_sizes[2];
    const int* src = ei;
    const int* dst = ei + E;

    const int nb   = (N + CHUNK - 1) / CHUNK;   // 391
    const int nblk = (E + EPB - 1) / EPB;       // 404

    // ws layout: payload | rowOff | dinv | xd | gd
    size_t off = 0;
    size_t payload_off = off;  off += (size_t)nblk * EPB * 8;
    size_t rowoff_off  = off;  off += (size_t)nblk * (nb + 1) * 4;
    off = (off + 7) & ~(size_t)7;
    size_t dinv_off    = off;  off += (size_t)N * 4;
    size_t xd_off      = off;  off += (size_t)N * 4;
    size_t gd_off      = off;  off += (size_t)N * 4;
    const size_t required = off;

    if (nb <= MAXNB && nb <= BLOCK_S && nblk <= MAXBLK && ws_size >= required) {
        char* wsb = (char*)d_ws;
        unsigned long long* payload = (unsigned long long*)(wsb + payload_off);
        unsigned int* rowOff = (unsigned int*)(wsb + rowoff_off);
        float* dinv = (float*)(wsb + dinv_off);
        float* xd   = (float*)(wsb + xd_off);
        float* gd   = (float*)(wsb + gd_off);

        scatter_kernel <<<nblk, BLOCK_S, 0, stream>>>(src, dst, w, rowOff, payload, E, nb);
        deg_dinv_kernel<<<nb,   BLOCK_A, 0, stream>>>(payload, rowOff, x, dinv, xd, N, nb, nblk);
        s_gamma_kernel <<<nb,   BLOCK_A, 0, stream>>>(payload, rowOff, dinv, xd, W1, b1, W2,
                                                      gd, N, nb, nblk);
        d_out_kernel   <<<nb,   BLOCK_A, 0, stream>>>(payload, rowOff, dinv, gd, b2,
                                                      out, N, nb, nblk);
    } else {
        // R3 fallback: global-atomic path (needs 4N floats of ws)
        float*  ws   = (float*)d_ws;
        float*  dinv = ws;
        float*  s    = ws + (size_t)N;
        float2* g    = (float2*)(ws + (size_t)2 * N);
        const int gridE  = (E + BLOCK - 1) / BLOCK;
        const int gridN  = (N + BLOCK - 1) / BLOCK;
        const int gridN2 = (2 * N + BLOCK - 1) / BLOCK;
        zero_kernel<<<gridN2, BLOCK, 0, stream>>>(ws, out, 2 * N);
        deg_kernel <<<gridE,  BLOCK, 0, stream>>>(dst, w, dinv, E);
        dinv_kernel<<<gridN,  BLOCK, 0, stream>>>(dinv, N);
        s_kernel   <<<gridE,  BLOCK, 0, stream>>>(src, dst, w, dinv, x, s, E);
        g_kernel   <<<gridN,  BLOCK, 0, stream>>>(s, dinv, x, W1, b1, W2, g, N);
        agg2_kernel<<<gridE,  BLOCK, 0, stream>>>(src, dst, w, dinv, g, out, E);
        out_kernel <<<gridN,  BLOCK, 0, stream>>>(out, dinv, g, b2, N);
    }
}